// Round 12
// baseline (120.975 us; speedup 1.0000x reference)
//
#include <hip/hip_runtime.h>
#include <hip/hip_fp16.h>
#include <math.h>

// MatchAttention fused forward — async global->LDS gather pipeline.
// B=2, H=W=64 (N=4096), C=256, h=8 (Ch=32), 7x7=49 window.
//
// R9-R11 lesson: any register-resident load batch gets collapsed by the
// register scheduler (VGPR 52/64/88; loads sunk to uses -> per-row drain).
// global_load_lds is a fire-and-forget DMA: per-lane GLOBAL address
// (scatter-gather), LDS dest = wave-uniform base + lane*16, tracked by
// vmcnt, zero VGPR per outstanding load. Double-buffered rows: issue row
// iy+1's 7 DMAs, s_waitcnt vmcnt(7), compute row iy from LDS via
// ds_read_b128 of each lane's own slot (conflict-free). No barriers —
// each pixel's 8 lanes are within one wave.
constexpr int B = 2, H = 64, W = 64, C = 256, NH = 8, CH = 32;
constexpr int R = 3, KW = 7, KK = 49, N = H * W;
constexpr int PIX = 32;  // pixel-heads per 256-thread block (8 lanes each)

template <int CTRL>
static __device__ __forceinline__ float dpp_mov(float v) {
  union { float f; int i; } u;
  u.f = v;
  u.i = __builtin_amdgcn_update_dpp(u.i, u.i, CTRL, 0xf, 0xf, true);
  return u.f;
}
#define DPP_QUAD_XOR1 0xB1     // quad_perm [1,0,3,2]
#define DPP_QUAD_XOR2 0x4E     // quad_perm [2,3,0,1]
#define DPP_HALF_MIRROR 0x141  // lane i -> 7-i within each 8-lane group

// async 16B gather-to-LDS; gaddr per-lane, laddr wave-uniform (+lane*16 by HW)
#define GLD16(gaddr, laddr)                                                   \
  __builtin_amdgcn_global_load_lds(                                           \
      (const __attribute__((address_space(1))) void*)(gaddr),                 \
      (__attribute__((address_space(3))) void*)(laddr), 16, 0, 0)

// pack k,v fp32 -> fp16 interleaved: [b][n][g][(k0..3 v0..3) x 8] = 128B
__global__ void __launch_bounds__(256) pack_kv_kernel(
    const float* __restrict__ kp, const float* __restrict__ vp,
    __half* __restrict__ kv) {
  const int idx = blockIdx.x * 256 + threadIdx.x;  // 0..524287
  const int e8 = idx & 7;
  const int g = (idx >> 3) & 7;
  const int bn = idx >> 6;  // 0..8191 = b*N+n
  const float4 kf = *(const float4*)(kp + (size_t)bn * C + g * CH + e8 * 4);
  const float4 vf = *(const float4*)(vp + (size_t)bn * C + g * CH + e8 * 4);
  __half2 o[4];
  o[0] = __floats2half2_rn(kf.x, kf.y);
  o[1] = __floats2half2_rn(kf.z, kf.w);
  o[2] = __floats2half2_rn(vf.x, vf.y);
  o[3] = __floats2half2_rn(vf.z, vf.w);
  *(float4*)(kv + ((size_t)(bn * NH + g) * 64 + e8 * 8)) = *(float4*)o;
}

__global__ void __launch_bounds__(256) match_attn_kernel(
    const float* __restrict__ moff, const float* __restrict__ qp,
    const __half* __restrict__ kvp, float* __restrict__ outp,
    float* __restrict__ attnp) {
  // per-wave double-buffered row tiles: 7 positions x 64 lanes x 16B = 7KB
  __shared__ __align__(16) char smem[4][2][KW * 1024];

  const int t = threadIdx.x;
  const int e8 = t & 7;  // which 4-channel slice of the head
  const int p = t >> 3;  // pixel within block, 0..31
  const int wv = t >> 6;
  const int lane16 = (t & 63) * 16;
  char* buf0 = &smem[wv][0][0];
  char* buf1 = &smem[wv][1][0];

  // XCD swizzle: blk&7 ~ XCD; XCD x owns (b,g) pairs {2x,2x+1}
  const int xcd = blockIdx.x & 7;
  const int rest = blockIdx.x >> 3;      // 0..255
  const int bg = xcd * 2 + (rest >> 7);  // 0..15
  const int slot = rest & 127;
  const int y = slot >> 1;
  const int x = (slot & 1) * PIX + p;
  const int g = bg & 7;
  const int b = bg >> 3;
  const int n = y * W + x;

  // per-pixel, per-head rounded (dy,dx); rintf == jnp.round (half-to-even)
  const float2 off = *(const float2*)(moff + ((size_t)(b * N + n) * NH + g) * 2);
  const int cy = y + (int)rintf(off.x);
  const int cx = x + (int)rintf(off.y);

  // clamped window offsets in BYTES into the packed kv image:
  // pixel stride 1024B (<<10), row stride 64KB (<<16)
  int pxo[KW], rowo[KW];
#pragma unroll
  for (int i = 0; i < KW; ++i) {
    pxo[i] = min(max(cx + i - R, 0), W - 1) << 10;
    rowo[i] = min(max(cy + i - R, 0), H - 1) << 16;
  }
  // per-lane gather base: b image + head + lane channel-chunk
  const char* kvimg = (const char*)kvp +
      (size_t)b * N * NH * 128 + g * 128 + e8 * 16;

  const int chn = g * CH + e8 * 4;
  const float4 q0 = *(const float4*)(qp + (size_t)(b * N + n) * C + chn);
  const __half2 q01 = __floats2half2_rn(q0.x, q0.y);
  const __half2 q23 = __floats2half2_rn(q0.z, q0.w);

  float ev7[KW];  // attn weights of the row this lane owns (lane e8 -> row e8)
#pragma unroll
  for (int i = 0; i < KW; ++i) ev7[i] = 0.f;
  float4 acc = {0.f, 0.f, 0.f, 0.f};  // unnormalized e-weighted V sum
  float d0 = 0.f, d1 = 0.f;           // two denom chains

  // prologue: row 0 in flight
#pragma unroll
  for (int ix = 0; ix < KW; ++ix)
    GLD16(kvimg + (rowo[0] + pxo[ix]), buf0 + (ix << 10));

  union KV { float4 f; __half2 h[4]; };
#pragma unroll
  for (int iy = 0; iy < KW; ++iy) {
    char* cur = (iy & 1) ? buf1 : buf0;
    char* nxt = (iy & 1) ? buf0 : buf1;
    if (iy + 1 < KW) {
      // nxt was last ds_read 2 rows ago; ensure those reads retired (WAR)
      __builtin_amdgcn_s_waitcnt(0xC07F);  // lgkmcnt(0)
#pragma unroll
      for (int ix = 0; ix < KW; ++ix)
        GLD16(kvimg + (rowo[iy + 1] + pxo[ix]), nxt + (ix << 10));
      __builtin_amdgcn_s_waitcnt(0x0F77);  // vmcnt(7): row iy has landed
    } else {
      __builtin_amdgcn_s_waitcnt(0x0F70);  // vmcnt(0): last row landed
    }
    const bool own = (iy == e8);  // uniform across the inner unroll
#pragma unroll
    for (int ix = 0; ix < KW; ++ix) {
      KV kv;
      kv.f = *(const float4*)(cur + (ix << 10) + lane16);  // ds_read_b128
      const __half2 d01h = __habs2(__hsub2(q01, kv.h[0]));
      const __half2 d23h = __habs2(__hsub2(q23, kv.h[1]));
      const float2 f01 = __half22float2(d01h);
      const float2 f23 = __half22float2(d23h);
      float s = (f01.x + f01.y) + (f23.x + f23.y);
      // 8-lane reduction entirely in the VALU pipe via DPP
      s += dpp_mov<DPP_QUAD_XOR1>(s);
      s += dpp_mov<DPP_QUAD_XOR2>(s);
      s += dpp_mov<DPP_HALF_MIRROR>(s);
      // sim=-L1<=0, L1~N(36,4.8^2): exp never underflows denom -> no max
      const float e = __expf(-s);
      if (ix & 1) d1 += e; else d0 += e;
      if (own) ev7[ix] = e;  // compile-time reg index, 1 cndmask
      const float2 v01 = __half22float2(kv.h[2]);
      const float2 v23 = __half22float2(kv.h[3]);
      acc.x += e * v01.x; acc.y += e * v01.y;
      acc.z += e * v23.x; acc.w += e * v23.y;
    }
  }
  const float inv = 1.0f / (d0 + d1);

  float4 o;
  o.x = acc.x * inv; o.y = acc.y * inv; o.z = acc.z * inv; o.w = acc.w * inv;
  *(float4*)(outp + (size_t)(b * N + n) * C + chn) = o;

  // lane e8 (<7) writes window row e8 of attn, normalized, exactly once
  if (e8 < KW) {
    float* attn_row = attnp + ((size_t)(b * N + n) * NH + g) * KK + e8 * KW;
#pragma unroll
    for (int ix = 0; ix < KW; ++ix) attn_row[ix] = ev7[ix] * inv;
  }
}

extern "C" void kernel_launch(void* const* d_in, const int* in_sizes, int n_in,
                              void* d_out, int out_size, void* d_ws, size_t ws_size,
                              hipStream_t stream) {
  const float* moff = (const float*)d_in[0];  // [B,N,h,2]
  const float* q    = (const float*)d_in[1];  // [B,N,C]
  const float* k    = (const float*)d_in[2];  // [B,N,C]
  const float* v    = (const float*)d_in[3];  // [B,N,C]
  float* out  = (float*)d_out;            // [B,N,C]
  float* attn = out + (size_t)B * N * C;  // [B,N,h,K]
  __half* kv = (__half*)d_ws;             // packed fp16 kv, 8.4 MB

  pack_kv_kernel<<<B * N * NH * 8 / 256, 256, 0, stream>>>(k, v, kv);
  const int grid = B * NH * N / PIX;  // 2048 blocks of 256 threads
  match_attn_kernel<<<grid, 256, 0, stream>>>(moff, q, kv, out, attn);
}

// Round 13
// 112.776 us; speedup vs baseline: 1.0727x; 1.0727x over previous
//
#include <hip/hip_runtime.h>
#include <hip/hip_fp16.h>
#include <math.h>

// MatchAttention fused forward — fp16-packed kv + backedge-pipelined rows.
// B=2, H=W=64 (N=4096), C=256, h=8 (Ch=32), 7x7=49 window.
//
// Ledger: the register scheduler collapses load batches whenever the row
// loop is fully unrolled (R9/R10: VGPR 52-64, loads sunk to uses, ~370cyc
// serial per load) but KEEPS them when loads cross a runtime-loop backedge
// (R8: VGPR 88). Structure here: runtime t+=2 loop (unroll disabled), two
// row buffers; row t+2 is issued before computing row t+1, so >=7 loads
// are structurally in flight during every compute block. kv stays fp16-
// packed [k4|v4]x8 per (pixel,head) line -> 49 gathers/wave (instruction
// floor: 6.1 per pixel-head at 16B/lane).
constexpr int B = 2, H = 64, W = 64, C = 256, NH = 8, CH = 32;
constexpr int R = 3, KW = 7, KK = 49, N = H * W;
constexpr int PIX = 32;  // pixel-heads per 256-thread block (8 lanes each)

template <int CTRL>
static __device__ __forceinline__ float dpp_mov(float v) {
  union { float f; int i; } u;
  u.f = v;
  u.i = __builtin_amdgcn_update_dpp(u.i, u.i, CTRL, 0xf, 0xf, true);
  return u.f;
}
#define DPP_QUAD_XOR1 0xB1     // quad_perm [1,0,3,2]
#define DPP_QUAD_XOR2 0x4E     // quad_perm [2,3,0,1]
#define DPP_HALF_MIRROR 0x141  // lane i -> 7-i within each 8-lane group

// pack k,v fp32 -> fp16 interleaved: [b][n][g][(k0..3 v0..3) x 8] = 128B
__global__ void __launch_bounds__(256) pack_kv_kernel(
    const float* __restrict__ kp, const float* __restrict__ vp,
    __half* __restrict__ kv) {
  const int idx = blockIdx.x * 256 + threadIdx.x;  // 0..524287
  const int e8 = idx & 7;
  const int g = (idx >> 3) & 7;
  const int bn = idx >> 6;  // 0..8191 = b*N+n
  const float4 kf = *(const float4*)(kp + (size_t)bn * C + g * CH + e8 * 4);
  const float4 vf = *(const float4*)(vp + (size_t)bn * C + g * CH + e8 * 4);
  __half2 o[4];
  o[0] = __floats2half2_rn(kf.x, kf.y);
  o[1] = __floats2half2_rn(kf.z, kf.w);
  o[2] = __floats2half2_rn(vf.x, vf.y);
  o[3] = __floats2half2_rn(vf.z, vf.w);
  *(float4*)(kv + ((size_t)(bn * NH + g) * 64 + e8 * 8)) = *(float4*)o;
}

union KV { float4 f; __half2 h[4]; };

__global__ void __launch_bounds__(256, 2) match_attn_kernel(
    const float* __restrict__ moff, const float* __restrict__ qp,
    const __half* __restrict__ kvp, float* __restrict__ outp,
    float* __restrict__ attnp) {
  const int t = threadIdx.x;
  const int e8 = t & 7;  // which 4-channel slice of the head
  const int p = t >> 3;  // pixel within block, 0..31

  // XCD swizzle: blk&7 ~ XCD; XCD x owns (b,g) pairs {2x,2x+1}
  const int xcd = blockIdx.x & 7;
  const int rest = blockIdx.x >> 3;      // 0..255
  const int bg = xcd * 2 + (rest >> 7);  // 0..15
  const int slot = rest & 127;
  const int y = slot >> 1;
  const int x = (slot & 1) * PIX + p;
  const int g = bg & 7;
  const int b = bg >> 3;
  const int n = y * W + x;

  // per-pixel, per-head rounded (dy,dx); rintf == jnp.round (half-to-even)
  const float2 off = *(const float2*)(moff + ((size_t)(b * N + n) * NH + g) * 2);
  const int cy = y + (int)rintf(off.x);
  const int cx = x + (int)rintf(off.y);

  // clamped x offsets in BYTES (pixel stride 1024B); y offset on the fly
  int pxo[KW];
#pragma unroll
  for (int i = 0; i < KW; ++i) pxo[i] = min(max(cx + i - R, 0), W - 1) << 10;
  // per-lane gather base: b image + head + lane channel-chunk
  const char* kvimg = (const char*)kvp +
      (size_t)b * N * NH * 128 + g * 128 + e8 * 16;

  const int chn = g * CH + e8 * 4;
  const float4 q0 = *(const float4*)(qp + (size_t)(b * N + n) * C + chn);
  const __half2 q01 = __floats2half2_rn(q0.x, q0.y);
  const __half2 q23 = __floats2half2_rn(q0.z, q0.w);

  float ev7[KW];  // attn weights of the row this lane owns (lane e8 -> row e8)
#pragma unroll
  for (int i = 0; i < KW; ++i) ev7[i] = 0.f;
  float4 acc = {0.f, 0.f, 0.f, 0.f};  // unnormalized e-weighted V sum
  float d0 = 0.f, d1 = 0.f;           // two denom chains

  // row offset (bytes, row stride 64KB), computed on the fly (no array)
#define ROWOFF(iy) (min(max(cy + (iy) - R, 0), H - 1) << 16)
#define LOADROW(buf, iy)                                            \
  {                                                                 \
    const int _ro = ROWOFF(iy);                                     \
    _Pragma("unroll") for (int ix = 0; ix < KW; ++ix)               \
        buf[ix].f = *(const float4*)(kvimg + (_ro + pxo[ix]));      \
  }
#define COMPROW(buf, iy)                                            \
  {                                                                 \
    const bool _own = ((iy) == e8);                                 \
    _Pragma("unroll") for (int ix = 0; ix < KW; ++ix) {             \
      const __half2 d01h = __habs2(__hsub2(q01, buf[ix].h[0]));     \
      const __half2 d23h = __habs2(__hsub2(q23, buf[ix].h[1]));     \
      const float2 f01 = __half22float2(d01h);                      \
      const float2 f23 = __half22float2(d23h);                      \
      float s = (f01.x + f01.y) + (f23.x + f23.y);                  \
      s += dpp_mov<DPP_QUAD_XOR1>(s);                               \
      s += dpp_mov<DPP_QUAD_XOR2>(s);                               \
      s += dpp_mov<DPP_HALF_MIRROR>(s);                             \
      const float e = __expf(-s); /* sim<=0: no max-shift needed */ \
      if (ix & 1) d1 += e; else d0 += e;                            \
      if (_own) ev7[ix] = e;                                        \
      const float2 v01 = __half22float2(buf[ix].h[2]);              \
      const float2 v23 = __half22float2(buf[ix].h[3]);              \
      acc.x += e * v01.x; acc.y += e * v01.y;                       \
      acc.z += e * v23.x; acc.w += e * v23.y;                       \
    }                                                               \
  }

  KV A[KW], Bf[KW];
  LOADROW(A, 0)  // prologue: row 0 in flight
#pragma clang loop unroll(disable)
  for (int ty = 0; ty < KW - 1; ty += 2) {  // ty = 0,2,4 — runtime backedge
    LOADROW(Bf, ty + 1)   // issue row ty+1 while row ty computes
    COMPROW(A, ty)
    LOADROW(A, ty + 2)    // issue row ty+2; crosses the backedge -> cannot
    COMPROW(Bf, ty + 1)   //   be sunk by the scheduler (R8 evidence)
  }
  COMPROW(A, KW - 1)      // epilogue: row 6

  const float inv = 1.0f / (d0 + d1);
  float4 o;
  o.x = acc.x * inv; o.y = acc.y * inv; o.z = acc.z * inv; o.w = acc.w * inv;
  *(float4*)(outp + (size_t)(b * N + n) * C + chn) = o;

  // lane e8 (<7) writes window row e8 of attn, normalized, exactly once
  if (e8 < KW) {
    float* attn_row = attnp + ((size_t)(b * N + n) * NH + g) * KK + e8 * KW;
#pragma unroll
    for (int ix = 0; ix < KW; ++ix) attn_row[ix] = ev7[ix] * inv;
  }
}

extern "C" void kernel_launch(void* const* d_in, const int* in_sizes, int n_in,
                              void* d_out, int out_size, void* d_ws, size_t ws_size,
                              hipStream_t stream) {
  const float* moff = (const float*)d_in[0];  // [B,N,h,2]
  const float* q    = (const float*)d_in[1];  // [B,N,C]
  const float* k    = (const float*)d_in[2];  // [B,N,C]
  const float* v    = (const float*)d_in[3];  // [B,N,C]
  float* out  = (float*)d_out;            // [B,N,C]
  float* attn = out + (size_t)B * N * C;  // [B,N,h,K]
  __half* kv = (__half*)d_ws;             // packed fp16 kv, 8.4 MB

  pack_kv_kernel<<<B * N * NH * 8 / 256, 256, 0, stream>>>(k, v, kv);
  const int grid = B * NH * N / PIX;  // 2048 blocks of 256 threads
  match_attn_kernel<<<grid, 256, 0, stream>>>(moff, q, kv, out, attn);
}